// Round 2
// baseline (886.674 us; speedup 1.0000x reference)
//
#include <hip/hip_runtime.h>

// MixConv: depthwise conv, 3 groups of 64 channels, k=3/5/7, same padding.
// x: [32,192,112,112] f32; w_k: [64,1,k,k] f32; out: [32,192,112,112] f32.
//
// Round 2: register-block HB=8 output rows per thread (rolling input-row
// window). Each thread computes an 8-high x 4-wide output patch. Per input
// row: 3 clamped float4 loads (branch-free, cndmask-zeroed at edges), then
// FMAs into up to min(K,8) accumulator rows. Cuts loads/output ~4x and gives
// the compiler independent loads to pipeline (round-1 kernel was latency-
// serialized at VGPR=16, VALUBusy 15%).

#define N_BATCH 32
#define C_TOTAL 192
#define HW 112
#define WQ 28          // 112/4 float4 units per row
#define HB 8           // output rows per thread
#define HT (HW / HB)   // 14 h-tiles
#define UNITS (HT * WQ)  // 392 units per plane

template <int K>
__global__ __launch_bounds__(256) void mixconv_kernel(
    const float* __restrict__ x, const float* __restrict__ w,
    float* __restrict__ out, int cbase) {
  constexpr int PAD = (K - 1) / 2;
  constexpr int NROWS = K + HB - 1;  // input rows touched per tile

  const int c = blockIdx.y;  // 0..63, block-uniform -> scalar weight loads
  const int n = blockIdx.z;

  float wr[K * K];
#pragma unroll
  for (int i = 0; i < K * K; ++i) wr[i] = w[c * K * K + i];

  const int unit = blockIdx.x * 256 + threadIdx.x;
  if (unit >= UNITS) return;
  const int ht = unit / WQ;
  const int wq = unit - ht * WQ;
  const int oh0 = ht * HB;

  const size_t plane = (size_t)(n * C_TOTAL + cbase + c) * (HW * HW);
  const float* xp = x + plane;

  // Clamped W-neighbor quad indices + validity (branch-free edge handling).
  const bool lv = (wq > 0);
  const bool rv = (wq < WQ - 1);
  const int lq = lv ? wq - 1 : wq;
  const int rq = rv ? wq + 1 : wq;

  float acc[HB][4];
#pragma unroll
  for (int o = 0; o < HB; ++o)
#pragma unroll
    for (int j = 0; j < 4; ++j) acc[o][j] = 0.f;

  const float4 zero = {0.f, 0.f, 0.f, 0.f};

#pragma unroll
  for (int r = 0; r < NROWS; ++r) {
    const int ih = oh0 + r - PAD;
    const bool hv = (ih >= 0) && (ih < HW);
    const int ihc = (ih < 0) ? 0 : ((ih >= HW) ? HW - 1 : ih);
    const float4* row = (const float4*)(xp + (size_t)ihc * HW);

    float4 L = row[lq];
    float4 M = row[wq];
    float4 R = row[rq];
    L = (hv && lv) ? L : zero;
    M = hv ? M : zero;
    R = (hv && rv) ? R : zero;

    // Input cols [wq*4-4, wq*4+7]; fully static-indexed -> registers.
    const float buf[12] = {L.x, L.y, L.z, L.w, M.x, M.y, M.z, M.w,
                           R.x, R.y, R.z, R.w};

#pragma unroll
    for (int o = 0; o < HB; ++o) {
      const int dy = r - o;  // tap row for output row o (compile-time)
      if (dy >= 0 && dy < K) {
#pragma unroll
        for (int dx = 0; dx < K; ++dx) {
          const float wv = wr[dy * K + dx];
#pragma unroll
          for (int j = 0; j < 4; ++j)
            acc[o][j] = fmaf(wv, buf[j + dx + 4 - PAD], acc[o][j]);
        }
      }
    }
  }

#pragma unroll
  for (int o = 0; o < HB; ++o) {
    float4 v = {acc[o][0], acc[o][1], acc[o][2], acc[o][3]};
    ((float4*)(out + plane + (size_t)(oh0 + o) * HW))[wq] = v;
  }
}

extern "C" void kernel_launch(void* const* d_in, const int* in_sizes, int n_in,
                              void* d_out, int out_size, void* d_ws,
                              size_t ws_size, hipStream_t stream) {
  const float* x = (const float*)d_in[0];
  const float* w3 = (const float*)d_in[1];
  const float* w5 = (const float*)d_in[2];
  const float* w7 = (const float*)d_in[3];
  float* out = (float*)d_out;

  const dim3 grid((UNITS + 255) / 256, 64, N_BATCH);
  const dim3 block(256);

  mixconv_kernel<3><<<grid, block, 0, stream>>>(x, w3, out, 0);
  mixconv_kernel<5><<<grid, block, 0, stream>>>(x, w5, out, 64);
  mixconv_kernel<7><<<grid, block, 0, stream>>>(x, w7, out, 128);
}

// Round 4
// 507.407 us; speedup vs baseline: 1.7475x; 1.7475x over previous
//
#include <hip/hip_runtime.h>

// MixConv: depthwise conv, 3 groups of 64 channels, k=3/5/7, same padding.
// x: [32,192,112,112] f32; w_k: [64,1,k,k] f32; out: [32,192,112,112] f32.
//
// Round 4: fused single dispatch; 8-wide x 2-row threads; wave-safe shuffle
// halo. Mapping: lane&15 = wq (14 of 16 active; 112/8=14 units per row),
// lane>>4 = row-pair within wave. Shuffle distance 1 only crosses a 16-lane
// group at wq==0 (lv-masked) or wq==13 (rv-masked) -> correct at all wave
// boundaries (round-3 bug was 28-wide runs crossing wave edges unmasked).
// All input-row loads issued branch-free up front (clamped ih + zero mask);
// horizontal halo from neighbor lanes' quads via __shfl (DS pipe) instead of
// extra L1 loads.

#define N_BATCH 32
#define C_TOTAL 192
#define HW 112
#define WQ2 14   // 8-wide units per row
#define ROWS_PER_BLOCK 16  // 2 waves * 4 groups * 2 rows

template <int K>
__device__ __forceinline__ void conv_plane(
    const float* __restrict__ x, const float* __restrict__ w,
    float* __restrict__ out, int cglob, int wc, int n, int rowbase) {
  constexpr int PAD = (K - 1) / 2;
  constexpr int NR = K + 1;  // input rows per 2-row output tile

  // Block-uniform weights -> scalar loads / SGPR broadcast.
  float wr[K * K];
#pragma unroll
  for (int i = 0; i < K * K; ++i) wr[i] = w[wc * K * K + i];

  const int l = threadIdx.x & 63;
  const int wv = threadIdx.x >> 6;  // wave in block (0..1)
  const int g = l >> 4;             // row-pair group 0..3
  const int wq = l & 15;            // 8-wide unit; active if < 14
  const bool act = (wq < WQ2);
  const int w0 = (act ? wq : WQ2 - 1) * 8;  // clamp idle lanes in-bounds
  const int oh0 = rowbase + wv * 8 + g * 2;

  const size_t plane = ((size_t)n * C_TOTAL + cglob) * (HW * HW);
  const float* xp = x + plane;

  const bool lv = (wq > 0);
  const bool rv = (wq < WQ2 - 1);
  const float4 zero4 = {0.f, 0.f, 0.f, 0.f};

  // ---- Phase 1: branch-free clamped loads, hv-masked (partner lanes in a
  // 16-group share oh0 -> identical hv, so masking before shuffle is safe).
  float4 Mv[NR][2];
#pragma unroll
  for (int r = 0; r < NR; ++r) {
    const int ih = oh0 + r - PAD;
    const bool hvr = (ih >= 0) && (ih < HW);
    const int ihc = (ih < 0) ? 0 : ((ih >= HW) ? HW - 1 : ih);
    const float* rp = xp + (size_t)ihc * HW + w0;
    float4 a = ((const float4*)rp)[0];
    float4 b = ((const float4*)rp)[1];
    Mv[r][0] = hvr ? a : zero4;
    Mv[r][1] = hvr ? b : zero4;
  }

  float acc[2][8];
#pragma unroll
  for (int o = 0; o < 2; ++o)
#pragma unroll
    for (int j = 0; j < 8; ++j) acc[o][j] = 0.f;

  // ---- Phase 2: shuffle halo + FMA.
#pragma unroll
  for (int r = 0; r < NR; ++r) {
    const float4 M0 = Mv[r][0];
    const float4 M1 = Mv[r][1];
    float4 L, R;
    L.x = __shfl_up(M1.x, 1);
    L.y = __shfl_up(M1.y, 1);
    L.z = __shfl_up(M1.z, 1);
    L.w = __shfl_up(M1.w, 1);
    R.x = __shfl_down(M0.x, 1);
    R.y = __shfl_down(M0.y, 1);
    R.z = __shfl_down(M0.z, 1);
    R.w = __shfl_down(M0.w, 1);
    L = lv ? L : zero4;
    R = rv ? R : zero4;

    // buf = input cols [w0-4, w0+12); fully static-indexed -> registers.
    const float buf[16] = {L.x,  L.y,  L.z,  L.w,  M0.x, M0.y, M0.z, M0.w,
                           M1.x, M1.y, M1.z, M1.w, R.x,  R.y,  R.z,  R.w};

#pragma unroll
    for (int o = 0; o < 2; ++o) {
      const int dy = r - o;  // compile-time tap row for output row oh0+o
      if (dy >= 0 && dy < K) {
#pragma unroll
        for (int dx = 0; dx < K; ++dx) {
          const float wt = wr[dy * K + dx];
#pragma unroll
          for (int j = 0; j < 8; ++j)
            acc[o][j] = fmaf(wt, buf[4 + j + dx - PAD], acc[o][j]);
        }
      }
    }
  }

  if (act) {
#pragma unroll
    for (int o = 0; o < 2; ++o) {
      float* op = out + plane + (size_t)(oh0 + o) * HW + w0;
      float4 v0 = {acc[o][0], acc[o][1], acc[o][2], acc[o][3]};
      float4 v1 = {acc[o][4], acc[o][5], acc[o][6], acc[o][7]};
      ((float4*)op)[0] = v0;
      ((float4*)op)[1] = v1;
    }
  }
}

__global__ __launch_bounds__(128) void mixconv_fused(
    const float* __restrict__ x, const float* __restrict__ w3,
    const float* __restrict__ w5, const float* __restrict__ w7,
    float* __restrict__ out) {
  const int cy = blockIdx.y;  // 0..191, block-uniform
  const int n = blockIdx.z;
  const int rowbase = blockIdx.x * ROWS_PER_BLOCK;
  if (cy < 64)
    conv_plane<3>(x, w3, out, cy, cy, n, rowbase);
  else if (cy < 128)
    conv_plane<5>(x, w5, out, cy, cy - 64, n, rowbase);
  else
    conv_plane<7>(x, w7, out, cy, cy - 128, n, rowbase);
}

extern "C" void kernel_launch(void* const* d_in, const int* in_sizes, int n_in,
                              void* d_out, int out_size, void* d_ws,
                              size_t ws_size, hipStream_t stream) {
  const float* x = (const float*)d_in[0];
  const float* w3 = (const float*)d_in[1];
  const float* w5 = (const float*)d_in[2];
  const float* w7 = (const float*)d_in[3];
  float* out = (float*)d_out;

  const dim3 grid(HW / ROWS_PER_BLOCK, C_TOTAL, N_BATCH);  // 7 x 192 x 32
  const dim3 block(128);
  mixconv_fused<<<grid, block, 0, stream>>>(x, w3, w5, w7, out);
}

// Round 5
// 393.490 us; speedup vs baseline: 2.2534x; 1.2895x over previous
//
#include <hip/hip_runtime.h>

// MixConv: depthwise conv, 3 groups of 64 channels, k=3/5/7, same padding.
// x: [32,192,112,112] f32; w_k: [64,1,k,k] f32; out: [32,192,112,112] f32.
//
// Round 5: LDS-staged tile. Block = 256 thr = 16 rows x 16 lanes; tile =
// 16 output rows x 112 cols; stage (16+K-1) input rows into LDS (zeros for
// out-of-image rows), barrier, compute from LDS. Lane u owns two 4-col
// quads: A at cols 4u, B (lane-REVERSED) at cols 108-4u; horizontal halo
// taps come from neighbor lanes via DPP row-shifts (16-lane DPP rows ==
// our groups; bound_ctrl=1 gives the zero at both image edges). Stores are
// lane-contiguous per instruction (fixes round-4's 1.41x write
// amplification from half-sector strided stores).

#define HW 112
#define TILE_H 16
#define LSTRIDE 544          // LDS row stride in bytes (136 dwords: +2 bank-quad/row)
#define NR_MAX (TILE_H + 6)  // 22 rows max (k=7)
#define C_TOTAL 192
#define N_BATCH 32

// DPP row (16-lane) shifts. ROW_SHR1: lane i <- lane i-1 (0 at row start).
//                           ROW_SHL1: lane i <- lane i+1 (0 at row end).
__device__ __forceinline__ float dpp_shr1(float v) {
  return __int_as_float(
      __builtin_amdgcn_update_dpp(0, __float_as_int(v), 0x111, 0xF, 0xF, true));
}
__device__ __forceinline__ float dpp_shl1(float v) {
  return __int_as_float(
      __builtin_amdgcn_update_dpp(0, __float_as_int(v), 0x101, 0xF, 0xF, true));
}

template <int K>
__device__ __forceinline__ void conv_tile(const float* __restrict__ x,
                                          const float* __restrict__ w,
                                          float* __restrict__ out, char* lds,
                                          int cglob, int wc, int n, int tile0) {
  constexpr int PAD = (K - 1) / 2;
  constexpr int NR = TILE_H + K - 1;  // staged rows
  constexpr int TOT = NR * 28;        // 16B units to stage (28 per 448B row)
  constexpr int ITERS = (TOT + 255) / 256;

  const int tid = threadIdx.x;
  const size_t plane = ((size_t)n * C_TOTAL + cglob) * (HW * HW);
  const float* xp = x + plane;

  // Block-uniform weights -> scalar loads / SGPR broadcast.
  float wr[K * K];
#pragma unroll
  for (int i = 0; i < K * K; ++i) wr[i] = w[wc * K * K + i];

  // ---- Stage rows [tile0-PAD, tile0+TILE_H+PAD) into LDS; zeros outside.
  const float4 z4 = {0.f, 0.f, 0.f, 0.f};
  float4 sv[ITERS];
#pragma unroll
  for (int it = 0; it < ITERS; ++it) {
    const int unit = tid + it * 256;
    const int row = unit / 28;
    const int cu = unit - row * 28;
    const int ih = tile0 - PAD + row;
    const bool ok = (unit < TOT) && (ih >= 0) && (ih < HW);
    const int ihc = (ih < 0) ? 0 : ((ih > HW - 1) ? HW - 1 : ih);
    const float4 t = *(const float4*)(xp + (size_t)ihc * HW + cu * 4);
    sv[it] = ok ? t : z4;
  }
#pragma unroll
  for (int it = 0; it < ITERS; ++it) {
    const int unit = tid + it * 256;
    const int row = unit / 28;
    const int cu = unit - row * 28;
    if (unit < TOT) *(float4*)(lds + row * LSTRIDE + cu * 16) = sv[it];
  }
  __syncthreads();

  // ---- Compute: group = output row (16 rows), lane u = col quads.
  const int myrow = tid >> 4;
  const int u = tid & 15;
  const char* base = lds + myrow * LSTRIDE;
  const int aA = u * 16;        // quad A: cols 4u      (byte 16u)
  const int aB = 432 - u * 16;  // quad B: cols 108-4u  (byte 432-16u)

  float acc[8];
#pragma unroll
  for (int i = 0; i < 8; ++i) acc[i] = 0.f;

#pragma unroll
  for (int r = 0; r < K; ++r) {  // tap row dy = r; LDS row = myrow + r
    const char* rb = base + r * LSTRIDE;
    const float4 MA = *(const float4*)(rb + aA);
    const float4 MB = *(const float4*)(rb + aB);

    // bufA = cols [4u-4, 4u+8); bufB = cols [104-4u, 116-4u) ascending.
    float bufA[12], bufB[12];
    bufA[0] = dpp_shr1(MA.x);  // LA = MA(u-1); u==0 -> 0 (left image edge)
    bufA[1] = dpp_shr1(MA.y);
    bufA[2] = dpp_shr1(MA.z);
    bufA[3] = dpp_shr1(MA.w);
    bufA[4] = MA.x; bufA[5] = MA.y; bufA[6] = MA.z; bufA[7] = MA.w;
    bufA[8] = dpp_shl1(MA.x);  // RA = MA(u+1); u==13 reads u=14 (cols 56-59)
    bufA[9] = dpp_shl1(MA.y);
    bufA[10] = dpp_shl1(MA.z);
    bufA[11] = dpp_shl1(MA.w);

    bufB[0] = dpp_shl1(MB.x);  // LB = MB(u+1); u==13 reads u=14 (cols 52-55)
    bufB[1] = dpp_shl1(MB.y);
    bufB[2] = dpp_shl1(MB.z);
    bufB[3] = dpp_shl1(MB.w);
    bufB[4] = MB.x; bufB[5] = MB.y; bufB[6] = MB.z; bufB[7] = MB.w;
    bufB[8] = dpp_shr1(MB.x);  // RB = MB(u-1); u==0 -> 0 (right image edge)
    bufB[9] = dpp_shr1(MB.y);
    bufB[10] = dpp_shr1(MB.z);
    bufB[11] = dpp_shr1(MB.w);

#pragma unroll
    for (int dx = 0; dx < K; ++dx) {
      const float wt = wr[r * K + dx];
#pragma unroll
      for (int j = 0; j < 4; ++j) {
        acc[j] = fmaf(wt, bufA[4 + j + dx - PAD], acc[j]);
        acc[4 + j] = fmaf(wt, bufB[4 + j + dx - PAD], acc[4 + j]);
      }
    }
  }

  if (u < 14) {  // lanes 14,15 only feed DPP halo
    float* orow = out + plane + (size_t)(tile0 + myrow) * HW;
    float4 vA = {acc[0], acc[1], acc[2], acc[3]};
    float4 vB = {acc[4], acc[5], acc[6], acc[7]};
    *(float4*)((char*)orow + u * 16) = vA;         // cols 4u
    *(float4*)((char*)orow + 432 - u * 16) = vB;   // cols 108-4u
  }
}

__global__ __launch_bounds__(256) void mixconv_lds(
    const float* __restrict__ x, const float* __restrict__ w3,
    const float* __restrict__ w5, const float* __restrict__ w7,
    float* __restrict__ out) {
  __shared__ __align__(16) char lds[NR_MAX * LSTRIDE];  // 11968 B
  const int cy = blockIdx.y;
  const int n = blockIdx.z;
  const int tile0 = blockIdx.x * TILE_H;
  if (cy < 64)
    conv_tile<3>(x, w3, out, lds, cy, cy, n, tile0);
  else if (cy < 128)
    conv_tile<5>(x, w5, out, lds, cy, cy - 64, n, tile0);
  else
    conv_tile<7>(x, w7, out, lds, cy, cy - 128, n, tile0);
}

extern "C" void kernel_launch(void* const* d_in, const int* in_sizes, int n_in,
                              void* d_out, int out_size, void* d_ws,
                              size_t ws_size, hipStream_t stream) {
  const float* x = (const float*)d_in[0];
  const float* w3 = (const float*)d_in[1];
  const float* w5 = (const float*)d_in[2];
  const float* w7 = (const float*)d_in[3];
  float* out = (float*)d_out;

  const dim3 grid(HW / TILE_H, C_TOTAL, N_BATCH);  // 7 x 192 x 32
  const dim3 block(256);
  mixconv_lds<<<grid, block, 0, stream>>>(x, w3, w5, w7, out);
}

// Round 6
// 350.576 us; speedup vs baseline: 2.5292x; 1.1224x over previous
//
#include <hip/hip_runtime.h>

// MixConv: depthwise conv, 3 groups of 64 channels, k=3/5/7, same padding.
// x: [32,192,112,112] f32; w_k: [64,1,k,k] f32; out: [32,192,112,112] f32.
//
// Round 6: LDS-staged slab (16 output rows x 112 cols per block), with
//  - LDS rows zero-padded by one quad on each side (30 quads = 480 B
//    stride) so the horizontal halo is 3 plain ds_read_b128 (L,M,R) --
//    no shuffles, no reversed mappings.
//  - Compute/store mapping unit = row*28 + q, row-major: output rows are
//    contiguous in memory, so every wave-store is a full-wave ASCENDING
//    CONTIGUOUS 1024B run. (Empirical store rule from R1/R4/R5 counters:
//    ascending contiguous = exact WRITE_SIZE; strided = 1.37x; reversed =
//    2.56x write amplification.)

#define HW 112
#define TILE_H 16
#define QROW 28              // data quads per row
#define LQ 30                // LDS quads per row incl 2 zero pads
#define LSTRIDE (LQ * 16)    // 480 B; -8 banks/row rotation
#define NR_MAX (TILE_H + 6)  // 22 staged rows max (k=7)
#define C_TOTAL 192
#define N_BATCH 32

template <int K>
__device__ __forceinline__ void conv_tile(const float* __restrict__ x,
                                          const float* __restrict__ w,
                                          float* __restrict__ out, char* lds,
                                          int cglob, int wc, int n, int tile0) {
  constexpr int PAD = (K - 1) / 2;
  constexpr int NR = TILE_H + K - 1;      // staged input rows
  constexpr int TOT = NR * QROW;          // staged 16B units
  constexpr int SITERS = (TOT + 255) / 256;
  constexpr int CTOT = TILE_H * QROW;     // 448 output quads per tile

  const int tid = threadIdx.x;
  const size_t plane = ((size_t)n * C_TOTAL + cglob) * (HW * HW);
  const float* xp = x + plane;

  // Block-uniform weights -> scalar loads / SGPR broadcast.
  float wr[K * K];
#pragma unroll
  for (int i = 0; i < K * K; ++i) wr[i] = w[wc * K * K + i];

  // ---- Stage rows [tile0-PAD, tile0+TILE_H+PAD) into LDS (zeros for
  // out-of-image rows); loads are full-wave ascending contiguous.
  const float4 z4 = {0.f, 0.f, 0.f, 0.f};
  float4 sv[SITERS];
#pragma unroll
  for (int it = 0; it < SITERS; ++it) {
    const int unit = tid + it * 256;
    const int row = unit / QROW;
    const int cu = unit - row * QROW;
    const int ih = tile0 - PAD + row;
    const bool ok = (unit < TOT) && (ih >= 0) && (ih < HW);
    const int ihc = (ih < 0) ? 0 : ((ih > HW - 1) ? HW - 1 : ih);
    const float4 t = *(const float4*)(xp + (size_t)ihc * HW + cu * 4);
    sv[it] = ok ? t : z4;
  }
#pragma unroll
  for (int it = 0; it < SITERS; ++it) {
    const int unit = tid + it * 256;
    const int row = unit / QROW;
    const int cu = unit - row * QROW;
    if (unit < TOT) *(float4*)(lds + row * LSTRIDE + 16 + cu * 16) = sv[it];
  }
  // Zero the left/right pad quads (cols -4..0 and 112..116).
  if (tid < NR) *(float4*)(lds + tid * LSTRIDE) = z4;
  if (tid >= 128 && tid < 128 + NR)
    *(float4*)(lds + (tid - 128) * LSTRIDE + (LQ - 1) * 16) = z4;
  __syncthreads();

  // ---- Compute: unit = row*28 + q, two batches; all-active or all-idle
  // waves; store = full-wave ascending contiguous runs.
  char* const outb = (char*)(out + plane + (size_t)tile0 * HW);
#pragma unroll
  for (int b = 0; b < 2; ++b) {
    const int unit = tid + b * 256;
    if (unit < CTOT) {
      const int row = unit / QROW;
      const int q = unit - row * QROW;
      // Window cols [4q-4, 4q+8) = LDS quads q, q+1, q+2 (data quad j is
      // LDS quad j+1).
      const char* base = lds + row * LSTRIDE + q * 16;

      float acc[4] = {0.f, 0.f, 0.f, 0.f};
#pragma unroll
      for (int r = 0; r < K; ++r) {
        const char* rb = base + r * LSTRIDE;
        const float4 L = *(const float4*)(rb);
        const float4 M = *(const float4*)(rb + 16);
        const float4 R = *(const float4*)(rb + 32);
        // Fully static-indexed -> registers.
        const float buf[12] = {L.x, L.y, L.z, L.w, M.x, M.y,
                               M.z, M.w, R.x, R.y, R.z, R.w};
#pragma unroll
        for (int dx = 0; dx < K; ++dx) {
          const float wt = wr[r * K + dx];
#pragma unroll
          for (int j = 0; j < 4; ++j)
            acc[j] = fmaf(wt, buf[4 + j + dx - PAD], acc[j]);
        }
      }
      float4 v = {acc[0], acc[1], acc[2], acc[3]};
      *(float4*)(outb + (size_t)unit * 16) = v;
    }
  }
}

__global__ __launch_bounds__(256) void mixconv_lds(
    const float* __restrict__ x, const float* __restrict__ w3,
    const float* __restrict__ w5, const float* __restrict__ w7,
    float* __restrict__ out) {
  __shared__ __align__(16) char lds[NR_MAX * LSTRIDE];  // 10560 B
  const int cy = blockIdx.y;
  const int n = blockIdx.z;
  const int tile0 = blockIdx.x * TILE_H;
  if (cy < 64)
    conv_tile<3>(x, w3, out, lds, cy, cy, n, tile0);
  else if (cy < 128)
    conv_tile<5>(x, w5, out, lds, cy, cy - 64, n, tile0);
  else
    conv_tile<7>(x, w7, out, lds, cy, cy - 128, n, tile0);
}

extern "C" void kernel_launch(void* const* d_in, const int* in_sizes, int n_in,
                              void* d_out, int out_size, void* d_ws,
                              size_t ws_size, hipStream_t stream) {
  const float* x = (const float*)d_in[0];
  const float* w3 = (const float*)d_in[1];
  const float* w5 = (const float*)d_in[2];
  const float* w7 = (const float*)d_in[3];
  float* out = (float*)d_out;

  const dim3 grid(HW / TILE_H, C_TOTAL, N_BATCH);  // 7 x 192 x 32
  const dim3 block(256);
  mixconv_lds<<<grid, block, 0, stream>>>(x, w3, w5, w7, out);
}

// Round 7
// 117.695 us; speedup vs baseline: 7.5337x; 2.9787x over previous
//
#include <hip/hip_runtime.h>

// MixConv: depthwise conv, 3 groups of 64 channels, k=3/5/7, same padding.
// x: [32,192,112,112] f32; w_k: [64,1,k,k] f32; out: [32,192,112,112] f32.
//
// Round 7 = Round 6 + ONE change: all global loads/stores go through a true
// clang ext_vector float4 and the output store uses
// __builtin_nontemporal_store (global_store_dwordx4 nt). Theory: HIP's
// struct-float4 stores were scalarized into 4x global_store_dword; under the
// fused kernel's L2 pressure, partially-dirty 64B lines were evicted between
// the partial stores, writing each output line to HBM up to 4x (WRITE_SIZE
// 3.67x compulsory at R6, growing with occupancy R4->R6). A single dwordx4
// wave-store fully dirties its lines in one instruction, making eviction
// timing irrelevant; nt also keeps streaming output out of L2.

#define HW 112
#define TILE_H 16
#define QROW 28              // data quads per row
#define LQ 30                // LDS quads per row incl 2 zero pads
#define LSTRIDE (LQ * 16)    // 480 B
#define NR_MAX (TILE_H + 6)  // 22 staged rows max (k=7)
#define C_TOTAL 192
#define N_BATCH 32

typedef float f4 __attribute__((ext_vector_type(4)));

template <int K>
__device__ __forceinline__ void conv_tile(const float* __restrict__ x,
                                          const float* __restrict__ w,
                                          float* __restrict__ out, char* lds,
                                          int cglob, int wc, int n, int tile0) {
  constexpr int PAD = (K - 1) / 2;
  constexpr int NR = TILE_H + K - 1;      // staged input rows
  constexpr int TOT = NR * QROW;          // staged 16B units
  constexpr int SITERS = (TOT + 255) / 256;
  constexpr int CTOT = TILE_H * QROW;     // 448 output quads per tile

  const int tid = threadIdx.x;
  const size_t plane = ((size_t)n * C_TOTAL + cglob) * (HW * HW);
  const float* xp = x + plane;

  // Block-uniform weights -> scalar loads / SGPR broadcast.
  float wr[K * K];
#pragma unroll
  for (int i = 0; i < K * K; ++i) wr[i] = w[wc * K * K + i];

  // ---- Stage rows [tile0-PAD, tile0+TILE_H+PAD) into LDS (zeros for
  // out-of-image rows); loads are full-wave ascending contiguous dwordx4.
  const f4 z4 = {0.f, 0.f, 0.f, 0.f};
  f4 sv[SITERS];
#pragma unroll
  for (int it = 0; it < SITERS; ++it) {
    const int unit = tid + it * 256;
    const int row = unit / QROW;
    const int cu = unit - row * QROW;
    const int ih = tile0 - PAD + row;
    const bool ok = (unit < TOT) && (ih >= 0) && (ih < HW);
    const int ihc = (ih < 0) ? 0 : ((ih > HW - 1) ? HW - 1 : ih);
    const f4 t = *(const f4*)(xp + (size_t)ihc * HW + cu * 4);
    sv[it] = ok ? t : z4;
  }
#pragma unroll
  for (int it = 0; it < SITERS; ++it) {
    const int unit = tid + it * 256;
    const int row = unit / QROW;
    const int cu = unit - row * QROW;
    if (unit < TOT) *(f4*)(lds + row * LSTRIDE + 16 + cu * 16) = sv[it];
  }
  // Zero the left/right pad quads (cols -4..0 and 112..116).
  if (tid < NR) *(f4*)(lds + tid * LSTRIDE) = z4;
  if (tid >= 128 && tid < 128 + NR)
    *(f4*)(lds + (tid - 128) * LSTRIDE + (LQ - 1) * 16) = z4;
  __syncthreads();

  // ---- Compute: unit = row*28 + q, two batches; store = one dwordx4 nt per
  // thread, full-wave ascending contiguous runs.
  char* const outb = (char*)(out + plane + (size_t)tile0 * HW);
#pragma unroll
  for (int b = 0; b < 2; ++b) {
    const int unit = tid + b * 256;
    if (unit < CTOT) {
      const int row = unit / QROW;
      const int q = unit - row * QROW;
      const char* base = lds + row * LSTRIDE + q * 16;

      float acc[4] = {0.f, 0.f, 0.f, 0.f};
#pragma unroll
      for (int r = 0; r < K; ++r) {
        const char* rb = base + r * LSTRIDE;
        const f4 L = *(const f4*)(rb);
        const f4 M = *(const f4*)(rb + 16);
        const f4 R = *(const f4*)(rb + 32);
        // Fully static-indexed -> registers.
        const float buf[12] = {L.x, L.y, L.z, L.w, M.x, M.y,
                               M.z, M.w, R.x, R.y, R.z, R.w};
#pragma unroll
        for (int dx = 0; dx < K; ++dx) {
          const float wt = wr[r * K + dx];
#pragma unroll
          for (int j = 0; j < 4; ++j)
            acc[j] = fmaf(wt, buf[4 + j + dx - PAD], acc[j]);
        }
      }
      f4 v = {acc[0], acc[1], acc[2], acc[3]};
      __builtin_nontemporal_store(v, (f4*)(outb + (size_t)unit * 16));
    }
  }
}

__global__ __launch_bounds__(256) void mixconv_lds(
    const float* __restrict__ x, const float* __restrict__ w3,
    const float* __restrict__ w5, const float* __restrict__ w7,
    float* __restrict__ out) {
  __shared__ __align__(16) char lds[NR_MAX * LSTRIDE];  // 10560 B
  const int cy = blockIdx.y;
  const int n = blockIdx.z;
  const int tile0 = blockIdx.x * TILE_H;
  if (cy < 64)
    conv_tile<3>(x, w3, out, lds, cy, cy, n, tile0);
  else if (cy < 128)
    conv_tile<5>(x, w5, out, lds, cy, cy - 64, n, tile0);
  else
    conv_tile<7>(x, w7, out, lds, cy, cy - 128, n, tile0);
}

extern "C" void kernel_launch(void* const* d_in, const int* in_sizes, int n_in,
                              void* d_out, int out_size, void* d_ws,
                              size_t ws_size, hipStream_t stream) {
  const float* x = (const float*)d_in[0];
  const float* w3 = (const float*)d_in[1];
  const float* w5 = (const float*)d_in[2];
  const float* w7 = (const float*)d_in[3];
  float* out = (float*)d_out;

  const dim3 grid(HW / TILE_H, C_TOTAL, N_BATCH);  // 7 x 192 x 32
  const dim3 block(256);
  mixconv_lds<<<grid, block, 0, stream>>>(x, w3, w5, w7, out);
}

// Round 8
// 114.716 us; speedup vs baseline: 7.7293x; 1.0260x over previous
//
#include <hip/hip_runtime.h>

// MixConv: depthwise conv, 3 groups of 64 channels, k=3/5/7, same padding.
// x: [32,192,112,112] f32; w_k: [64,1,k,k] f32; out: [32,192,112,112] f32.
//
// Round 8 = Round 7 + ONE change: TILE_H 16 -> 28 (4 tiles/column) to cut
// the vertical-halo re-fetch (staged rows / output rows: k=7 1.375x ->
// 1.214x, avg 1.25x -> 1.14x). Round 7's fix (true dwordx4 nt stores via
// ext_vector + __builtin_nontemporal_store) eliminated the 3.7x write
// amplification (350 -> 118 us); we are now ~89% of achievable HBM BW and
// the halo is the main identifiable remaining overhead.

#define HW 112
#define TILE_H 28
#define QROW 28              // data quads per row
#define LQ 30                // LDS quads per row incl 2 zero pads
#define LSTRIDE (LQ * 16)    // 480 B
#define NR_MAX (TILE_H + 6)  // 34 staged rows max (k=7)
#define C_TOTAL 192
#define N_BATCH 32

typedef float f4 __attribute__((ext_vector_type(4)));

template <int K>
__device__ __forceinline__ void conv_tile(const float* __restrict__ x,
                                          const float* __restrict__ w,
                                          float* __restrict__ out, char* lds,
                                          int cglob, int wc, int n, int tile0) {
  constexpr int PAD = (K - 1) / 2;
  constexpr int NR = TILE_H + K - 1;      // staged input rows
  constexpr int TOT = NR * QROW;          // staged 16B units
  constexpr int SITERS = (TOT + 255) / 256;
  constexpr int CTOT = TILE_H * QROW;     // 784 output quads per tile
  constexpr int CITERS = (CTOT + 255) / 256;

  const int tid = threadIdx.x;
  const size_t plane = ((size_t)n * C_TOTAL + cglob) * (HW * HW);
  const float* xp = x + plane;

  // Block-uniform weights -> scalar loads / SGPR broadcast.
  float wr[K * K];
#pragma unroll
  for (int i = 0; i < K * K; ++i) wr[i] = w[wc * K * K + i];

  // ---- Stage rows [tile0-PAD, tile0+TILE_H+PAD) into LDS (zeros for
  // out-of-image rows); loads are full-wave ascending contiguous dwordx4.
  const f4 z4 = {0.f, 0.f, 0.f, 0.f};
  f4 sv[SITERS];
#pragma unroll
  for (int it = 0; it < SITERS; ++it) {
    const int unit = tid + it * 256;
    const int row = unit / QROW;
    const int cu = unit - row * QROW;
    const int ih = tile0 - PAD + row;
    const bool ok = (unit < TOT) && (ih >= 0) && (ih < HW);
    const int ihc = (ih < 0) ? 0 : ((ih > HW - 1) ? HW - 1 : ih);
    const f4 t = *(const f4*)(xp + (size_t)ihc * HW + cu * 4);
    sv[it] = ok ? t : z4;
  }
#pragma unroll
  for (int it = 0; it < SITERS; ++it) {
    const int unit = tid + it * 256;
    const int row = unit / QROW;
    const int cu = unit - row * QROW;
    if (unit < TOT) *(f4*)(lds + row * LSTRIDE + 16 + cu * 16) = sv[it];
  }
  // Zero the left/right pad quads (cols -4..0 and 112..116).
  if (tid < NR) *(f4*)(lds + tid * LSTRIDE) = z4;
  if (tid >= 128 && tid < 128 + NR)
    *(f4*)(lds + (tid - 128) * LSTRIDE + (LQ - 1) * 16) = z4;
  __syncthreads();

  // ---- Compute: unit = row*28 + q; store = one dwordx4 nt per thread,
  // full-wave ascending contiguous runs.
  char* const outb = (char*)(out + plane + (size_t)tile0 * HW);
#pragma unroll
  for (int b = 0; b < CITERS; ++b) {
    const int unit = tid + b * 256;
    if (unit < CTOT) {
      const int row = unit / QROW;
      const int q = unit - row * QROW;
      const char* base = lds + row * LSTRIDE + q * 16;

      float acc[4] = {0.f, 0.f, 0.f, 0.f};
#pragma unroll
      for (int r = 0; r < K; ++r) {
        const char* rb = base + r * LSTRIDE;
        const f4 L = *(const f4*)(rb);
        const f4 M = *(const f4*)(rb + 16);
        const f4 R = *(const f4*)(rb + 32);
        // Fully static-indexed -> registers.
        const float buf[12] = {L.x, L.y, L.z, L.w, M.x, M.y,
                               M.z, M.w, R.x, R.y, R.z, R.w};
#pragma unroll
        for (int dx = 0; dx < K; ++dx) {
          const float wt = wr[r * K + dx];
#pragma unroll
          for (int j = 0; j < 4; ++j)
            acc[j] = fmaf(wt, buf[4 + j + dx - PAD], acc[j]);
        }
      }
      f4 v = {acc[0], acc[1], acc[2], acc[3]};
      __builtin_nontemporal_store(v, (f4*)(outb + (size_t)unit * 16));
    }
  }
}

__global__ __launch_bounds__(256) void mixconv_lds(
    const float* __restrict__ x, const float* __restrict__ w3,
    const float* __restrict__ w5, const float* __restrict__ w7,
    float* __restrict__ out) {
  __shared__ __align__(16) char lds[NR_MAX * LSTRIDE];  // 16320 B
  const int cy = blockIdx.y;
  const int n = blockIdx.z;
  const int tile0 = blockIdx.x * TILE_H;
  if (cy < 64)
    conv_tile<3>(x, w3, out, lds, cy, cy, n, tile0);
  else if (cy < 128)
    conv_tile<5>(x, w5, out, lds, cy, cy - 64, n, tile0);
  else
    conv_tile<7>(x, w7, out, lds, cy, cy - 128, n, tile0);
}

extern "C" void kernel_launch(void* const* d_in, const int* in_sizes, int n_in,
                              void* d_out, int out_size, void* d_ws,
                              size_t ws_size, hipStream_t stream) {
  const float* x = (const float*)d_in[0];
  const float* w3 = (const float*)d_in[1];
  const float* w5 = (const float*)d_in[2];
  const float* w7 = (const float*)d_in[3];
  float* out = (float*)d_out;

  const dim3 grid(HW / TILE_H, C_TOTAL, N_BATCH);  // 4 x 192 x 32
  const dim3 block(256);
  mixconv_lds<<<grid, block, 0, stream>>>(x, w3, w5, w7, out);
}

// Round 9
// 108.937 us; speedup vs baseline: 8.1394x; 1.0531x over previous
//
#include <hip/hip_runtime.h>

// MixConv: depthwise conv, 3 groups of 64 channels, k=3/5/7, same padding.
// x: [32,192,112,112] f32; w_k: [64,1,k,k] f32; out: [32,192,112,112] f32.
//
// Round 9 = Round 8 + 2-row x 4-col register blocking from LDS (each thread's
// 12-float window per tap row feeds TWO output rows: DS bytes/elt 6(K+1) vs
// 12K, avg -40%) and LSTRIDE 480 -> 496 B (31 quads; 2-row lane-group bank
// shift 24, 4-row 16 -- 480 had 4-row stride == 0 mod 32 banks).
// Stores stay full-wave ascending contiguous dwordx4 nt (two instructions,
// each covering complete 448 B row-runs / full 64 B lines -- the R7 fix that
// removed the 3.7x write amplification).

#define HW 112
#define TILE_H 28
#define QROW 28              // data quads per row
#define LSTRIDE 496          // 31 quads: 28 data + 2 zero pads + 1 spare
#define NR_MAX (TILE_H + 6)  // 34 staged rows max (k=7)
#define C_TOTAL 192
#define N_BATCH 32

typedef float f4 __attribute__((ext_vector_type(4)));

template <int K>
__device__ __forceinline__ void conv_tile(const float* __restrict__ x,
                                          const float* __restrict__ w,
                                          float* __restrict__ out, char* lds,
                                          int cglob, int wc, int n, int tile0) {
  constexpr int PAD = (K - 1) / 2;
  constexpr int NR = TILE_H + K - 1;      // staged input rows
  constexpr int TOT = NR * QROW;          // staged 16B units
  constexpr int SITERS = (TOT + 255) / 256;
  constexpr int CTOT = (TILE_H / 2) * QROW;  // 392 2-row units per tile

  const int tid = threadIdx.x;
  const size_t plane = ((size_t)n * C_TOTAL + cglob) * (HW * HW);
  const float* xp = x + plane;

  // Block-uniform weights -> scalar loads / SGPR broadcast.
  float wr[K * K];
#pragma unroll
  for (int i = 0; i < K * K; ++i) wr[i] = w[wc * K * K + i];

  // ---- Stage rows [tile0-PAD, tile0+TILE_H+PAD) into LDS (zeros for
  // out-of-image rows); loads are full-wave ascending contiguous dwordx4.
  const f4 z4 = {0.f, 0.f, 0.f, 0.f};
  f4 sv[SITERS];
#pragma unroll
  for (int it = 0; it < SITERS; ++it) {
    const int unit = tid + it * 256;
    const int row = unit / QROW;
    const int cu = unit - row * QROW;
    const int ih = tile0 - PAD + row;
    const bool ok = (unit < TOT) && (ih >= 0) && (ih < HW);
    const int ihc = (ih < 0) ? 0 : ((ih > HW - 1) ? HW - 1 : ih);
    const f4 t = *(const f4*)(xp + (size_t)ihc * HW + cu * 4);
    sv[it] = ok ? t : z4;
  }
#pragma unroll
  for (int it = 0; it < SITERS; ++it) {
    const int unit = tid + it * 256;
    const int row = unit / QROW;
    const int cu = unit - row * QROW;
    if (unit < TOT) *(f4*)(lds + row * LSTRIDE + 16 + cu * 16) = sv[it];
  }
  // Zero the left/right pad quads (cols -4..0 and 112..116).
  if (tid < NR) *(f4*)(lds + tid * LSTRIDE) = z4;
  if (tid >= 128 && tid < 128 + NR)
    *(f4*)(lds + (tid - 128) * LSTRIDE + 29 * 16) = z4;
  __syncthreads();

  // ---- Compute: unit = row-pair*28 + q; each thread -> 2 rows x 4 cols.
  char* const outb = (char*)(out + plane + (size_t)tile0 * HW);
#pragma unroll
  for (int b = 0; b < 2; ++b) {
    const int unit = tid + b * 256;
    if (unit < CTOT) {
      const int rp = unit / QROW;
      const int q = unit - rp * QROW;
      const char* base = lds + rp * 2 * LSTRIDE + q * 16;

      float acc[2][4] = {{0.f, 0.f, 0.f, 0.f}, {0.f, 0.f, 0.f, 0.f}};
#pragma unroll
      for (int r = 0; r < K + 1; ++r) {  // tap rows for output rows rp*2(+1)
        const char* rb = base + r * LSTRIDE;
        const f4 L = *(const f4*)(rb);
        const f4 M = *(const f4*)(rb + 16);
        const f4 R = *(const f4*)(rb + 32);
        // Fully static-indexed -> registers.
        const float buf[12] = {L.x, L.y, L.z, L.w, M.x, M.y,
                               M.z, M.w, R.x, R.y, R.z, R.w};
#pragma unroll
        for (int o = 0; o < 2; ++o) {
          const int dy = r - o;  // compile-time tap row for output row o
          if (dy >= 0 && dy < K) {
#pragma unroll
            for (int dx = 0; dx < K; ++dx) {
              const float wt = wr[dy * K + dx];
#pragma unroll
              for (int j = 0; j < 4; ++j)
                acc[o][j] = fmaf(wt, buf[4 + j + dx - PAD], acc[o][j]);
            }
          }
        }
      }
      // Two nt stores; each instruction's lane runs are ascending contiguous
      // full 448B rows (28 lanes/row) -> full 64B lines, no amplification.
      char* const o0 = outb + (size_t)(rp * 2) * (HW * 4) + q * 16;
      f4 v0 = {acc[0][0], acc[0][1], acc[0][2], acc[0][3]};
      f4 v1 = {acc[1][0], acc[1][1], acc[1][2], acc[1][3]};
      __builtin_nontemporal_store(v0, (f4*)(o0));
      __builtin_nontemporal_store(v1, (f4*)(o0 + HW * 4));
    }
  }
}

__global__ __launch_bounds__(256) void mixconv_lds(
    const float* __restrict__ x, const float* __restrict__ w3,
    const float* __restrict__ w5, const float* __restrict__ w7,
    float* __restrict__ out) {
  __shared__ __align__(16) char lds[NR_MAX * LSTRIDE];  // 16864 B
  const int cy = blockIdx.y;
  const int n = blockIdx.z;
  const int tile0 = blockIdx.x * TILE_H;
  if (cy < 64)
    conv_tile<3>(x, w3, out, lds, cy, cy, n, tile0);
  else if (cy < 128)
    conv_tile<5>(x, w5, out, lds, cy, cy - 64, n, tile0);
  else
    conv_tile<7>(x, w7, out, lds, cy, cy - 128, n, tile0);
}

extern "C" void kernel_launch(void* const* d_in, const int* in_sizes, int n_in,
                              void* d_out, int out_size, void* d_ws,
                              size_t ws_size, hipStream_t stream) {
  const float* x = (const float*)d_in[0];
  const float* w3 = (const float*)d_in[1];
  const float* w5 = (const float*)d_in[2];
  const float* w7 = (const float*)d_in[3];
  float* out = (float*)d_out;

  const dim3 grid(HW / TILE_H, C_TOTAL, N_BATCH);  // 4 x 192 x 32
  const dim3 block(256);
  mixconv_lds<<<grid, block, 0, stream>>>(x, w3, w5, w7, out);
}